// Round 3
// baseline (6762.145 us; speedup 1.0000x reference)
//
#include <hip/hip_runtime.h>
#include <math.h>

#define NFFT   1024
#define NH     512
#define HOP    64
#define NMELS  80
#define NFR    512
#define NBINS  513
#define NITER  300
#define SIGLEN 33728
#define NSEG   527
#define NT     256
#define NB2    256
#define NT2    128

// ---- workspace layout (4B units) ----
#define TBL_WIN  0          // win[1024]
#define TBL_TWR  1024       // twr[256]
#define TBL_TWI  1280       // twi[256]
#define TBL_W1R  1536       // w1r[513]
#define TBL_W1I  2056       // w1i[513]
#define FGEN     2624       // Fgen[512]  frame-generation flags
#define OFF_MAG  4096       // mag[512*513]
#define OFF_IWS  266752     // iws[33728]
#define OFF_F    300480     // F parity-0 [512*1024]
#define OFF_F2   824768     // F parity-1 [512*1024]

typedef unsigned long long u64;
typedef unsigned int u32;

// ---- coherent (agent-scope, L3-point) accessors ----
__device__ __forceinline__ float4 coh_load4(const float* p) {
    u64 a = __hip_atomic_load((const u64*)p,       __ATOMIC_RELAXED, __HIP_MEMORY_SCOPE_AGENT);
    u64 b = __hip_atomic_load((const u64*)(p + 2), __ATOMIC_RELAXED, __HIP_MEMORY_SCOPE_AGENT);
    float2 fa, fb;
    __builtin_memcpy(&fa, &a, 8);
    __builtin_memcpy(&fb, &b, 8);
    return make_float4(fa.x, fa.y, fb.x, fb.y);
}
__device__ __forceinline__ void coh_store4(float* p, float4 v) {
    float2 fa = make_float2(v.x, v.y), fb = make_float2(v.z, v.w);
    u64 a, b;
    __builtin_memcpy(&a, &fa, 8);
    __builtin_memcpy(&b, &fb, 8);
    __hip_atomic_store((u64*)p,       a, __ATOMIC_RELAXED, __HIP_MEMORY_SCOPE_AGENT);
    __hip_atomic_store((u64*)(p + 2), b, __ATOMIC_RELAXED, __HIP_MEMORY_SCOPE_AGENT);
}
__device__ __forceinline__ float coh_load1(const float* p) {
    u32 a = __hip_atomic_load((const u32*)p, __ATOMIC_RELAXED, __HIP_MEMORY_SCOPE_AGENT);
    float f;
    __builtin_memcpy(&f, &a, 4);
    return f;
}
__device__ __forceinline__ void flag_store(int* p, int v) {
    __hip_atomic_store(p, v, __ATOMIC_RELAXED, __HIP_MEMORY_SCOPE_AGENT);
}
__device__ __forceinline__ int flag_load(const int* p) {
    return __hip_atomic_load(p, __ATOMIC_RELAXED, __HIP_MEMORY_SCOPE_AGENT);
}

// ---- radix-4 Stockham stage (verified body), j in [0,128) ----
template<int P, int SH, bool INV>
__device__ __forceinline__ void r4b(const float* __restrict__ sR, const float* __restrict__ sI,
                                    float* __restrict__ dR, float* __restrict__ dI,
                                    const float* twr, const float* twi, int j) {
    int k  = j & (P - 1);
    int d0 = ((j - k) << 2) + k;
    float x0r = sR[j],       x0i = sI[j];
    float x1r = sR[j + 128], x1i = sI[j + 128];
    float x2r = sR[j + 256], x2i = sI[j + 256];
    float x3r = sR[j + 384], x3i = sI[j + 384];
    int tb = k << SH;
    float c1 = twr[tb], s1 = twi[tb];
    if (INV) s1 = -s1;
    float c2 = c1 * c1 - s1 * s1, s2 = 2.f * c1 * s1;
    float c3 = c1 * c2 - s1 * s2, s3 = c1 * s2 + s1 * c2;
    float a1r = x1r * c1 - x1i * s1, a1i = x1r * s1 + x1i * c1;
    float a2r = x2r * c2 - x2i * s2, a2i = x2r * s2 + x2i * c2;
    float a3r = x3r * c3 - x3i * s3, a3i = x3r * s3 + x3i * c3;
    float t0r = x0r + a2r, t0i = x0i + a2i;
    float t1r = x0r - a2r, t1i = x0i - a2i;
    float t2r = a1r + a3r, t2i = a1i + a3i;
    float t3r = a1r - a3r, t3i = a1i - a3i;
    float i3r = INV ? -t3i : t3i;
    float i3i = INV ?  t3r : -t3r;
    dR[d0]         = t0r + t2r;  dI[d0]         = t0i + t2i;
    dR[d0 + P]     = t1r + i3r;  dI[d0 + P]     = t1i + i3i;
    dR[d0 + 2 * P] = t0r - t2r;  dI[d0 + 2 * P] = t0i - t2i;
    dR[d0 + 3 * P] = t1r - i3r;  dI[d0 + 3 * P] = t1i - i3i;
}

// ================= k_init (round-3/5 verified, unchanged) ===================
struct __align__(16) SMemI {
    float xb[NFFT];
    float C0r[NH], C0i[NH];
    float C1r[NH], C1i[NH];
    float win[NFFT];
    float twr[256], twi[256];
    float mag[516];
};

extern "C" __global__ __launch_bounds__(NT)
void k_init(const float* __restrict__ mel,
            const float* __restrict__ invmel,
            float* __restrict__ ws) {
    __shared__ SMemI sm;
    const int tid = threadIdx.x;
    const int t   = blockIdx.x;

    for (int n = tid; n < NFFT; n += NT) {
        double a = (2.0 * 3.14159265358979323846) * (double)n / 1024.0;
        sm.win[n] = (float)(0.5 - 0.5 * cos(a));
    }
    for (int j = tid; j < 256; j += NT) {
        double a = (2.0 * 3.14159265358979323846) * (double)j / 512.0;
        sm.twr[j] = (float)cos(a);
        sm.twi[j] = (float)(-sin(a));
    }
    __syncthreads();
    if (t == 0) {
        for (int n = tid; n < NFFT; n += NT) ws[TBL_WIN + n] = sm.win[n];
        for (int j = tid; j < 256; j += NT) {
            ws[TBL_TWR + j] = sm.twr[j];
            ws[TBL_TWI + j] = sm.twi[j];
        }
        for (int k = tid; k < NBINS; k += NT) {
            double a = (2.0 * 3.14159265358979323846) * (double)k / 1024.0;
            ws[TBL_W1R + k] = (float)cos(a);
            ws[TBL_W1I + k] = (float)sin(a);
        }
        for (int i = tid; i < NFR; i += NT)
            ((int*)ws)[FGEN + i] = 0;
    }

    for (int p = t * NT + tid; p < SIGLEN; p += NFR * NT) {
        int tq = p >> 6, io = p & 63;
        float s = 0.f;
#pragma unroll
        for (int m = 0; m < 16; ++m) {
            int tp = tq - m;
            if (tp >= 0 && tp < NFR) {
                float w = sm.win[io + (m << 6)];
                s += w * w;
            }
        }
        ws[OFF_IWS + p] = (s > 1e-11f) ? (1.0f / s) : 1.0f;
    }

    if (tid < NMELS) sm.xb[tid] = exp10f(mel[tid * NFR + t]);
    __syncthreads();
    for (int k = tid; k < NBINS; k += NT) {
        const float* row = invmel + k * NMELS;
        float s = 0.f;
#pragma unroll 8
        for (int j = 0; j < NMELS; ++j) s += row[j] * sm.xb[j];
        ws[OFF_MAG + t * NBINS + k] = s;
        sm.mag[k] = s;
    }
    __syncthreads();

    for (int k = tid; k < NH; k += NT) {
        float xr = sm.mag[k], yr = sm.mag[512 - k];
        double a = (2.0 * 3.14159265358979323846) * (double)k / 1024.0;
        float c = (float)cos(a), s = (float)sin(a);
        float dr = xr - yr;
        sm.C1r[k] = ((xr + yr) - s * dr) * (1.0f / 1024.0f);
        sm.C1i[k] = (c * dr) * (1.0f / 1024.0f);
    }
    __syncthreads();
    if (tid < 128) {
        float x0r = sm.C1r[tid],       x0i = sm.C1i[tid];
        float x1r = sm.C1r[tid + 128], x1i = sm.C1i[tid + 128];
        float x2r = sm.C1r[tid + 256], x2i = sm.C1i[tid + 256];
        float x3r = sm.C1r[tid + 384], x3i = sm.C1i[tid + 384];
        float t0r = x0r + x2r, t0i = x0i + x2i;
        float t1r = x0r - x2r, t1i = x0i - x2i;
        float t2r = x1r + x3r, t2i = x1i + x3i;
        float t3r = x1r - x3r, t3i = x1i - x3i;
        float4 vr = make_float4(t0r + t2r, t1r - t3i, t0r - t2r, t1r + t3i);
        float4 vi = make_float4(t0i + t2i, t1i + t3r, t0i - t2i, t1i - t3r);
        ((float4*)sm.C0r)[tid] = vr;
        ((float4*)sm.C0i)[tid] = vi;
    }
    __syncthreads();
    if (tid < 128) r4b<4, 5, true>(sm.C0r, sm.C0i, sm.C1r, sm.C1i, sm.twr, sm.twi, tid);
    __syncthreads();
    if (tid < 128) r4b<16, 3, true>(sm.C1r, sm.C1i, sm.C0r, sm.C0i, sm.twr, sm.twi, tid);
    __syncthreads();
    if (tid < 128) r4b<64, 1, true>(sm.C0r, sm.C0i, sm.C1r, sm.C1i, sm.twr, sm.twi, tid);
    __syncthreads();
    {
        float c = sm.twr[tid], s = -sm.twi[tid];
        float x0r = sm.C1r[tid], x0i = sm.C1i[tid];
        float x1r = sm.C1r[tid + 256], x1i = sm.C1i[tid + 256];
        float ar = x1r * c - x1i * s, ai = x1r * s + x1i * c;
        sm.C0r[tid]       = x0r + ar;  sm.C0i[tid]       = x0i + ai;
        sm.C0r[tid + 256] = x0r - ar;  sm.C0i[tid + 256] = x0i - ai;
    }
    __syncthreads();

    float4 w4 = ((float4*)sm.win)[tid];
    float4 o;
    o.x = w4.x * sm.C0r[2 * tid];
    o.y = w4.y * sm.C0i[2 * tid];
    o.z = w4.z * sm.C0r[2 * tid + 1];
    o.w = w4.w * sm.C0i[2 * tid + 1];
    *(float4*)&ws[OFF_F + (t << 10) + (tid << 2)] = o;
}

// ============== persistent Griffin-Lim: WAVE-PER-FRAME, zero-barrier ========
//
// One 64-lane wave owns one frame: the whole FFT pipeline runs through a
// wave-private LDS region, so same-wave program order (+ compiler lgkmcnt)
// replaces every __syncthreads. Phase bodies are the VERIFIED block versions
// with tid -> (lane, e) substitution, fully unrolled (static indexing).
// Cross-frame sync = R2 single-flag-round scheme: parity double-buffered F,
// monotone fgen; release = s_waitcnt vmcnt(0) + flag store (per wave).
// 256 blocks x 128 threads (2 independent waves/block); one pre-loop
// __syncthreads only for the shared twiddle staging.

struct __align__(16) SM2 {
    float twr[256], twi[256];
    float C0r[2][NH], C0i[2][NH];
    float C1r[2][NH], C1i[2][NH];
};

extern "C" __global__ __launch_bounds__(NT2)
void k_persist(float* __restrict__ ws, float* __restrict__ out) {
    __shared__ SM2 sm;
    const int tid  = threadIdx.x;
    const int wid  = tid >> 6;
    const int lane = tid & 63;
    const int f    = (blockIdx.x << 1) | wid;   // frame owned by this wave

    const float* tbl  = ws;
    const float* magg = ws + OFF_MAG;
    const float* iws  = ws + OFF_IWS;
    float* F0 = ws + OFF_F;
    float* F1 = ws + OFF_F2;
    int*   fgen = (int*)ws + FGEN;

    float* C0r = sm.C0r[wid]; float* C0i = sm.C0i[wid];
    float* C1r = sm.C1r[wid]; float* C1i = sm.C1i[wid];
    const float* twr = sm.twr; const float* twi = sm.twi;

    // ---- one-time staging: shared twiddles (only block-wide sync, pre-loop)
    if (tid < 64)       ((float4*)sm.twr)[tid]      = ((const float4*)(tbl + TBL_TWR))[tid];
    else                ((float4*)sm.twi)[tid - 64] = ((const float4*)(tbl + TBL_TWI))[tid - 64];
    __syncthreads();

    // ---- per-lane register tables ----
    // win/iws for this lane's 16 contiguous samples (shared by pack & store)
    float4 win4[4], iws4[4];
#pragma unroll
    for (int e = 0; e < 4; ++e) {
        win4[e] = ((const float4*)(tbl + TBL_WIN))[(lane << 2) + e];
        iws4[e] = *(const float4*)&iws[(f << 6) + (lane << 4) + (e << 2)];
    }
    // projection tables for v = lane + 64e
    float pm_a[4], pm_b[4], pw1ra[4], pw1ia[4], pw1rb[4], pw1ib[4];
    float m_ny = 0.f;
    {
        const int s0 = f * NBINS;
#pragma unroll
        for (int e = 0; e < 4; ++e) {
            int v = lane + (e << 6);
            if (v == 0) {
                pm_a[e] = magg[s0]; pm_b[e] = magg[s0 + 256];
                m_ny = magg[s0 + 512];
                pw1ra[e] = 1.f; pw1ia[e] = 0.f; pw1rb[e] = 0.f; pw1ib[e] = 1.f;
            } else {
                pm_a[e] = magg[s0 + v]; pm_b[e] = magg[s0 + 512 - v];
                pw1ra[e] = tbl[TBL_W1R + v];       pw1ia[e] = tbl[TBL_W1I + v];
                pw1rb[e] = tbl[TBL_W1R + 512 - v]; pw1ib[e] = tbl[TBL_W1I + 512 - v];
            }
        }
    }

#pragma unroll 1
    for (int it = 1; it <= NITER; ++it) {
        // ---- wait: frames f-15..f+15 at generation it-1 (per-wave poll) ----
        if (it > 1 && lane < 31) {
            int tp = f - 15 + lane;
            if (tp >= 0 && tp < NFR)
                while (flag_load(fgen + tp) < it - 1)
                    __builtin_amdgcn_s_sleep(1);
        }
        asm volatile("" ::: "memory");   // no hoisting of gathers above the wait

        const float* Fs = (it & 1) ? F0 : F1;   // source parity (it-1)&1
        float*       Fd = (it & 1) ? F1 : F0;   // dest parity it&1

        // ---- fused OLA gather + iws + window -> packed z in C1 ----
        // virtual tid v = 4*lane + e covers samples 4v..4v+3
#pragma unroll
        for (int e = 0; e < 4; ++e) {
            const int v    = (lane << 2) + e;
            const int i0v  = v << 2;
            const int tq   = f + (v >> 4);
            const int foff = i0v & 63;
            float4 acc = make_float4(0.f, 0.f, 0.f, 0.f);
#pragma unroll
            for (int m = 0; m < 16; ++m) {
                int tp = tq - m;
                if (tp >= 0 && tp < NFR) {
                    float4 x = coh_load4(&Fs[(tp << 10) + foff + (m << 6)]);
                    acc.x += x.x; acc.y += x.y; acc.z += x.z; acc.w += x.w;
                }
            }
            float xx = acc.x * iws4[e].x;
            float xy = acc.y * iws4[e].y;
            float xz = acc.z * iws4[e].z;
            float xw = acc.w * iws4[e].w;
            const int n0 = v << 1;
            C1r[n0]     = xx * win4[e].x;
            C1i[n0]     = xy * win4[e].y;
            C1r[n0 + 1] = xz * win4[e].z;
            C1i[n0 + 1] = xw * win4[e].w;
        }

        // ---- forward FFT: C1 -> C0 (verified bodies, j = lane + 64e) ----
#pragma unroll
        for (int e = 0; e < 2; ++e) {
            const int j = lane + (e << 6);
            float x0r = C1r[j],       x0i = C1i[j];
            float x1r = C1r[j + 128], x1i = C1i[j + 128];
            float x2r = C1r[j + 256], x2i = C1i[j + 256];
            float x3r = C1r[j + 384], x3i = C1i[j + 384];
            float t0r = x0r + x2r, t0i = x0i + x2i;
            float t1r = x0r - x2r, t1i = x0i - x2i;
            float t2r = x1r + x3r, t2i = x1i + x3i;
            float t3r = x1r - x3r, t3i = x1i - x3i;
            float4 vr = make_float4(t0r + t2r, t1r + t3i, t0r - t2r, t1r - t3i);
            float4 vi = make_float4(t0i + t2i, t1i - t3r, t0i - t2i, t1i + t3r);
            ((float4*)C0r)[j] = vr;
            ((float4*)C0i)[j] = vi;
        }
        r4b<4, 5, false>(C0r, C0i, C1r, C1i, twr, twi, lane);
        r4b<4, 5, false>(C0r, C0i, C1r, C1i, twr, twi, lane + 64);
        r4b<16, 3, false>(C1r, C1i, C0r, C0i, twr, twi, lane);
        r4b<16, 3, false>(C1r, C1i, C0r, C0i, twr, twi, lane + 64);
        r4b<64, 1, false>(C0r, C0i, C1r, C1i, twr, twi, lane);
        r4b<64, 1, false>(C0r, C0i, C1r, C1i, twr, twi, lane + 64);
#pragma unroll
        for (int e = 0; e < 4; ++e) {
            const int v = lane + (e << 6);
            float c = twr[v], s = twi[v];
            float x0r = C1r[v], x0i = C1i[v];
            float x1r = C1r[v + 256], x1i = C1i[v + 256];
            float ar = x1r * c - x1i * s, ai = x1r * s + x1i * c;
            C0r[v]       = x0r + ar;  C0i[v]       = x0i + ai;
            C0r[v + 256] = x0r - ar;  C0i[v + 256] = x0i - ai;
        }

        // ---- fused unpack + phase projection + iFFT prep: C0 -> C1 ----
#pragma unroll
        for (int e = 0; e < 4; ++e) {
            const int v = lane + (e << 6);
            if (v == 0) {
                float zr = C0r[0], zi = C0i[0];
                float e0 = zr + zi;
                float e5 = zr - zi;
                float X0 = pm_a[0] * e0 / fmaxf(1e-8f, fabsf(e0));
                float X5 = m_ny    * e5 / fmaxf(1e-8f, fabsf(e5));
                C1r[0] = (X0 + X5) * (1.0f / 1024.0f);
                C1i[0] = (X0 - X5) * (1.0f / 1024.0f);
                float z6r = C0r[256], z6i = C0i[256];
                float sc6 = pm_b[0] / fmaxf(1e-8f, sqrtf(z6r * z6r + z6i * z6i));
                float X6r = z6r * sc6, X6i = -z6i * sc6;
                C1r[256] = X6r * (2.0f / 1024.0f);
                C1i[256] = -X6i * (2.0f / 1024.0f);
            } else {
                const int j2 = 512 - v;
                float zr = C0r[v], zi = C0i[v];
                float ur = C0r[j2], ui = C0i[j2];
                float er = 0.5f * (zr + ur), ei = 0.5f * (zi - ui);
                float dr = zr - ur,          di = zi + ui;
                float odr = 0.5f * di, odi = -0.5f * dr;
                float e1r = er + pw1ra[e] * odr + pw1ia[e] * odi;
                float e1i = ei + pw1ra[e] * odi - pw1ia[e] * odr;
                float e2r =  er + pw1rb[e] * odr - pw1ib[e] * odi;
                float e2i = -ei - pw1rb[e] * odi - pw1ib[e] * odr;
                float sc1 = pm_a[e] / fmaxf(1e-8f, sqrtf(e1r * e1r + e1i * e1i));
                float sc2 = pm_b[e] / fmaxf(1e-8f, sqrtf(e2r * e2r + e2i * e2i));
                float X1r = e1r * sc1, X1i = e1i * sc1;
                float X2r = e2r * sc2, X2i = e2i * sc2;
                float Er = X1r + X2r, Ei = X1i - X2i;
                float Dr = X1r - X2r, Di = X1i + X2i;
                float wdr = pw1ra[e] * Dr - pw1ia[e] * Di, wdi = pw1ra[e] * Di + pw1ia[e] * Dr;
                C1r[v] = (Er - wdi) * (1.0f / 1024.0f);
                C1i[v] = (Ei + wdr) * (1.0f / 1024.0f);
                float wdr2 = -pw1rb[e] * Dr - pw1ib[e] * Di, wdi2 = pw1rb[e] * Di - pw1ib[e] * Dr;
                C1r[j2] = (Er - wdi2) * (1.0f / 1024.0f);
                C1i[j2] = (-Ei + wdr2) * (1.0f / 1024.0f);
            }
        }

        // ---- inverse FFT: C1 -> C0 ----
#pragma unroll
        for (int e = 0; e < 2; ++e) {
            const int j = lane + (e << 6);
            float x0r = C1r[j],       x0i = C1i[j];
            float x1r = C1r[j + 128], x1i = C1i[j + 128];
            float x2r = C1r[j + 256], x2i = C1i[j + 256];
            float x3r = C1r[j + 384], x3i = C1i[j + 384];
            float t0r = x0r + x2r, t0i = x0i + x2i;
            float t1r = x0r - x2r, t1i = x0i - x2i;
            float t2r = x1r + x3r, t2i = x1i + x3i;
            float t3r = x1r - x3r, t3i = x1i - x3i;
            float4 vr = make_float4(t0r + t2r, t1r - t3i, t0r - t2r, t1r + t3i);
            float4 vi = make_float4(t0i + t2i, t1i + t3r, t0i - t2i, t1i - t3r);
            ((float4*)C0r)[j] = vr;
            ((float4*)C0i)[j] = vi;
        }
        r4b<4, 5, true>(C0r, C0i, C1r, C1i, twr, twi, lane);
        r4b<4, 5, true>(C0r, C0i, C1r, C1i, twr, twi, lane + 64);
        r4b<16, 3, true>(C1r, C1i, C0r, C0i, twr, twi, lane);
        r4b<16, 3, true>(C1r, C1i, C0r, C0i, twr, twi, lane + 64);
        r4b<64, 1, true>(C0r, C0i, C1r, C1i, twr, twi, lane);
        r4b<64, 1, true>(C0r, C0i, C1r, C1i, twr, twi, lane + 64);
#pragma unroll
        for (int e = 0; e < 4; ++e) {
            const int v = lane + (e << 6);
            float c = twr[v], s = -twi[v];
            float x0r = C1r[v], x0i = C1i[v];
            float x1r = C1r[v + 256], x1i = C1i[v + 256];
            float ar = x1r * c - x1i * s, ai = x1r * s + x1i * c;
            C0r[v]       = x0r + ar;  C0i[v]       = x0i + ai;
            C0r[v + 256] = x0r - ar;  C0i[v + 256] = x0i - ai;
        }

        // ---- store windowed frame (dest parity), publish fgen[f] = it ----
#pragma unroll
        for (int e = 0; e < 4; ++e) {
            const int v  = (lane << 2) + e;
            const int n0 = v << 1;
            float4 o;
            o.x = win4[e].x * C0r[n0];
            o.y = win4[e].y * C0i[n0];
            o.z = win4[e].z * C0r[n0 + 1];
            o.w = win4[e].w * C0i[n0 + 1];
            coh_store4(&Fd[(f << 10) + (v << 2)], o);
        }
        asm volatile("s_waitcnt vmcnt(0)" ::: "memory");   // F[f]@it at L3
        if (lane == 0)
            flag_store(fgen + f, it);
    }

    // ===== final non-redundant OLA @ gen NITER (even -> parity 0 -> F0) =====
    if (lane < 31) {
        int tp = f - 15 + lane;
        if (tp >= 0 && tp < NFR)
            while (flag_load(fgen + tp) < NITER)
                __builtin_amdgcn_s_sleep(1);
    }
    asm volatile("" ::: "memory");
    {
        float acc = 0.f;
#pragma unroll
        for (int m = 0; m < 16; ++m) {
            int tp = f - m;
            if (tp >= 0 && tp < NFR)
                acc += coh_load1(&F0[(tp << 10) + lane + (m << 6)]);
        }
        out[(f << 6) + lane] = acc * iws[(f << 6) + lane];
    }
    if (f >= 497) {
        const int s2 = f + 15;   // segments 512..526
        float acc = 0.f;
#pragma unroll
        for (int m = 0; m < 16; ++m) {
            int tp = s2 - m;
            if (tp >= 0 && tp < NFR)
                acc += coh_load1(&F0[(tp << 10) + lane + (m << 6)]);
        }
        out[(s2 << 6) + lane] = acc * iws[(s2 << 6) + lane];
    }
}

extern "C" void kernel_launch(void* const* d_in, const int* in_sizes, int n_in,
                              void* d_out, int out_size, void* d_ws, size_t ws_size,
                              hipStream_t stream) {
    const float* mel    = (const float*)d_in[0];
    const float* invmel = (const float*)d_in[1];
    float* out = (float*)d_out;
    float* ws  = (float*)d_ws;

    k_init<<<NFR, NT, 0, stream>>>(mel, invmel, ws);
    k_persist<<<NB2, NT2, 0, stream>>>(ws, out);
}

// Round 4
// 2980.101 us; speedup vs baseline: 2.2691x; 2.2691x over previous
//
#include <hip/hip_runtime.h>
#include <math.h>

#define NFFT   1024
#define NH     512
#define HOP    64
#define NMELS  80
#define NFR    512
#define NBINS  513
#define NITER  300
#define SIGLEN 33728
#define NSEG   527
#define NT     256
#define NB     512

// ---- workspace layout (4B units) ----
#define TBL_WIN  0          // win[1024]
#define TBL_TWR  1024       // twr[256]
#define TBL_TWI  1280       // twi[256]
#define TBL_W1R  1536       // w1r[513]
#define TBL_W1I  2056       // w1i[513]
#define OFF_MAG  4096       // mag[512*513]            ends 266752
#define OFF_IWS  266752     // iws[33728]              ends 300480
#define OFF_F    300480     // F parity-0 [512*1024]   ends 824768
#define OFF_F2   824768     // F parity-1 [512*1024]   ends 1349056
#define FGEN     1349056    // Fgen[512*16] padded: one flag per 64B line

typedef unsigned long long u64;
typedef unsigned int u32;

// ---- coherent (agent-scope, L3-point) accessors ----
__device__ __forceinline__ float4 coh_load4(const float* p) {
    u64 a = __hip_atomic_load((const u64*)p,       __ATOMIC_RELAXED, __HIP_MEMORY_SCOPE_AGENT);
    u64 b = __hip_atomic_load((const u64*)(p + 2), __ATOMIC_RELAXED, __HIP_MEMORY_SCOPE_AGENT);
    float2 fa, fb;
    __builtin_memcpy(&fa, &a, 8);
    __builtin_memcpy(&fb, &b, 8);
    return make_float4(fa.x, fa.y, fb.x, fb.y);
}
__device__ __forceinline__ void coh_store4(float* p, float4 v) {
    float2 fa = make_float2(v.x, v.y), fb = make_float2(v.z, v.w);
    u64 a, b;
    __builtin_memcpy(&a, &fa, 8);
    __builtin_memcpy(&b, &fb, 8);
    __hip_atomic_store((u64*)p,       a, __ATOMIC_RELAXED, __HIP_MEMORY_SCOPE_AGENT);
    __hip_atomic_store((u64*)(p + 2), b, __ATOMIC_RELAXED, __HIP_MEMORY_SCOPE_AGENT);
}
__device__ __forceinline__ float coh_load1(const float* p) {
    u32 a = __hip_atomic_load((const u32*)p, __ATOMIC_RELAXED, __HIP_MEMORY_SCOPE_AGENT);
    float f;
    __builtin_memcpy(&f, &a, 4);
    return f;
}
__device__ __forceinline__ void flag_store(int* p, int v) {
    __hip_atomic_store(p, v, __ATOMIC_RELAXED, __HIP_MEMORY_SCOPE_AGENT);
}
__device__ __forceinline__ int flag_load(const int* p) {
    return __hip_atomic_load(p, __ATOMIC_RELAXED, __HIP_MEMORY_SCOPE_AGENT);
}
__device__ __forceinline__ float4 f4add(float4 a, float4 b) {
    return make_float4(a.x + b.x, a.y + b.y, a.z + b.z, a.w + b.w);
}

// ---- radix-4 Stockham stage (verified), caller guards tid<128 ----
template<int P, int SH, bool INV>
__device__ __forceinline__ void r4b(const float* __restrict__ sR, const float* __restrict__ sI,
                                    float* __restrict__ dR, float* __restrict__ dI,
                                    const float* twr, const float* twi, int j) {
    int k  = j & (P - 1);
    int d0 = ((j - k) << 2) + k;
    float x0r = sR[j],       x0i = sI[j];
    float x1r = sR[j + 128], x1i = sI[j + 128];
    float x2r = sR[j + 256], x2i = sI[j + 256];
    float x3r = sR[j + 384], x3i = sI[j + 384];
    int tb = k << SH;
    float c1 = twr[tb], s1 = twi[tb];
    if (INV) s1 = -s1;
    float c2 = c1 * c1 - s1 * s1, s2 = 2.f * c1 * s1;
    float c3 = c1 * c2 - s1 * s2, s3 = c1 * s2 + s1 * c2;
    float a1r = x1r * c1 - x1i * s1, a1i = x1r * s1 + x1i * c1;
    float a2r = x2r * c2 - x2i * s2, a2i = x2r * s2 + x2i * c2;
    float a3r = x3r * c3 - x3i * s3, a3i = x3r * s3 + x3i * c3;
    float t0r = x0r + a2r, t0i = x0i + a2i;
    float t1r = x0r - a2r, t1i = x0i - a2i;
    float t2r = a1r + a3r, t2i = a1i + a3i;
    float t3r = a1r - a3r, t3i = a1i - a3i;
    float i3r = INV ? -t3i : t3i;
    float i3i = INV ?  t3r : -t3r;
    dR[d0]         = t0r + t2r;  dI[d0]         = t0i + t2i;
    dR[d0 + P]     = t1r + i3r;  dI[d0 + P]     = t1i + i3i;
    dR[d0 + 2 * P] = t0r - t2r;  dI[d0 + 2 * P] = t0i - t2i;
    dR[d0 + 3 * P] = t1r - i3r;  dI[d0 + 3 * P] = t1i - i3i;
}

// ================= k_init (round-3/5 verified) ===============================
struct __align__(16) SMemI {
    float xb[NFFT];
    float C0r[NH], C0i[NH];
    float C1r[NH], C1i[NH];
    float win[NFFT];
    float twr[256], twi[256];
    float mag[516];
};

extern "C" __global__ __launch_bounds__(NT)
void k_init(const float* __restrict__ mel,
            const float* __restrict__ invmel,
            float* __restrict__ ws) {
    __shared__ SMemI sm;
    const int tid = threadIdx.x;
    const int t   = blockIdx.x;

    for (int n = tid; n < NFFT; n += NT) {
        double a = (2.0 * 3.14159265358979323846) * (double)n / 1024.0;
        sm.win[n] = (float)(0.5 - 0.5 * cos(a));
    }
    for (int j = tid; j < 256; j += NT) {
        double a = (2.0 * 3.14159265358979323846) * (double)j / 512.0;
        sm.twr[j] = (float)cos(a);
        sm.twi[j] = (float)(-sin(a));
    }
    __syncthreads();
    if (t == 0) {
        for (int n = tid; n < NFFT; n += NT) ws[TBL_WIN + n] = sm.win[n];
        for (int j = tid; j < 256; j += NT) {
            ws[TBL_TWR + j] = sm.twr[j];
            ws[TBL_TWI + j] = sm.twi[j];
        }
        for (int k = tid; k < NBINS; k += NT) {
            double a = (2.0 * 3.14159265358979323846) * (double)k / 1024.0;
            ws[TBL_W1R + k] = (float)cos(a);
            ws[TBL_W1I + k] = (float)sin(a);
        }
        // zero padded frame-generation flags (gen 0 = k_init frames)
        for (int i = tid; i < NFR * 16; i += NT)
            ((int*)ws)[FGEN + i] = 0;
    }

    for (int p = t * NT + tid; p < SIGLEN; p += NFR * NT) {
        int tq = p >> 6, io = p & 63;
        float s = 0.f;
#pragma unroll
        for (int m = 0; m < 16; ++m) {
            int tp = tq - m;
            if (tp >= 0 && tp < NFR) {
                float w = sm.win[io + (m << 6)];
                s += w * w;
            }
        }
        ws[OFF_IWS + p] = (s > 1e-11f) ? (1.0f / s) : 1.0f;
    }

    if (tid < NMELS) sm.xb[tid] = exp10f(mel[tid * NFR + t]);
    __syncthreads();
    for (int k = tid; k < NBINS; k += NT) {
        const float* row = invmel + k * NMELS;
        float s = 0.f;
#pragma unroll 8
        for (int j = 0; j < NMELS; ++j) s += row[j] * sm.xb[j];
        ws[OFF_MAG + t * NBINS + k] = s;
        sm.mag[k] = s;
    }
    __syncthreads();

    for (int k = tid; k < NH; k += NT) {
        float xr = sm.mag[k], yr = sm.mag[512 - k];
        double a = (2.0 * 3.14159265358979323846) * (double)k / 1024.0;
        float c = (float)cos(a), s = (float)sin(a);
        float dr = xr - yr;
        sm.C1r[k] = ((xr + yr) - s * dr) * (1.0f / 1024.0f);
        sm.C1i[k] = (c * dr) * (1.0f / 1024.0f);
    }
    __syncthreads();
    if (tid < 128) {
        float x0r = sm.C1r[tid],       x0i = sm.C1i[tid];
        float x1r = sm.C1r[tid + 128], x1i = sm.C1i[tid + 128];
        float x2r = sm.C1r[tid + 256], x2i = sm.C1i[tid + 256];
        float x3r = sm.C1r[tid + 384], x3i = sm.C1i[tid + 384];
        float t0r = x0r + x2r, t0i = x0i + x2i;
        float t1r = x0r - x2r, t1i = x0i - x2i;
        float t2r = x1r + x3r, t2i = x1i + x3i;
        float t3r = x1r - x3r, t3i = x1i - x3i;
        float4 vr = make_float4(t0r + t2r, t1r - t3i, t0r - t2r, t1r + t3i);
        float4 vi = make_float4(t0i + t2i, t1i + t3r, t0i - t2i, t1i - t3r);
        ((float4*)sm.C0r)[tid] = vr;
        ((float4*)sm.C0i)[tid] = vi;
    }
    __syncthreads();
    if (tid < 128) r4b<4, 5, true>(sm.C0r, sm.C0i, sm.C1r, sm.C1i, sm.twr, sm.twi, tid);
    __syncthreads();
    if (tid < 128) r4b<16, 3, true>(sm.C1r, sm.C1i, sm.C0r, sm.C0i, sm.twr, sm.twi, tid);
    __syncthreads();
    if (tid < 128) r4b<64, 1, true>(sm.C0r, sm.C0i, sm.C1r, sm.C1i, sm.twr, sm.twi, tid);
    __syncthreads();
    {
        float c = sm.twr[tid], s = -sm.twi[tid];
        float x0r = sm.C1r[tid], x0i = sm.C1i[tid];
        float x1r = sm.C1r[tid + 256], x1i = sm.C1i[tid + 256];
        float ar = x1r * c - x1i * s, ai = x1r * s + x1i * c;
        sm.C0r[tid]       = x0r + ar;  sm.C0i[tid]       = x0i + ai;
        sm.C0r[tid + 256] = x0r - ar;  sm.C0i[tid + 256] = x0i - ai;
    }
    __syncthreads();

    float4 w4 = ((float4*)sm.win)[tid];
    float4 o;
    o.x = w4.x * sm.C0r[2 * tid];
    o.y = w4.y * sm.C0i[2 * tid];
    o.z = w4.z * sm.C0r[2 * tid + 1];
    o.w = w4.w * sm.C0i[2 * tid + 1];
    *(float4*)&ws[OFF_F + (t << 10) + (tid << 2)] = o;
}

// ============== persistent Griffin-Lim: fused pipeline, R4 tuning ===========
//
// R2 structure (verified): 512 blocks x 256 threads, block t owns frame t;
// redundant local OLA gather from F[t-15..t+15]; parity double-buffered F;
// single flag round per iteration (monotone fgen). R4 deltas:
//  * flags padded to one per 64B line (no false sharing, 16x fewer pollers
//    per L3 line),
//  * throttled polls (check, then s_sleep(4)),
//  * interior-block gather loads all 16 float4 into independent registers
//    (full memory-level parallelism) + pairwise-tree sum.

struct __align__(16) SM1 {
    float C0r[NH], C0i[NH];
    float C1r[NH], C1i[NH];
    float twr[256], twi[256];
};

extern "C" __global__ __launch_bounds__(NT)
void k_persist(float* __restrict__ ws, float* __restrict__ out) {
    __shared__ SM1 sm;
    const int tid = threadIdx.x;
    const int t   = blockIdx.x;       // frame owned
    const int i0  = tid << 2;
    const int j2  = 512 - tid;
    const int n0  = tid << 1;

    const float* tbl  = ws;
    const float* magg = ws + OFF_MAG;
    const float* iws  = ws + OFF_IWS;
    float* F0 = ws + OFF_F;
    float* F1 = ws + OFF_F2;
    int*   fgen = (int*)ws + FGEN;    // stride-16 padded

    // ---- one-time staging ----
    if (tid < 64)       ((float4*)sm.twr)[tid]      = ((const float4*)(tbl + TBL_TWR))[tid];
    else if (tid < 128) ((float4*)sm.twi)[tid - 64] = ((const float4*)(tbl + TBL_TWI))[tid - 64];

    float4 w4   = ((const float4*)(tbl + TBL_WIN))[tid];
    float4 iws4 = *(const float4*)&iws[(t << 6) + i0];
    float m_a, m_b, m_ny = 0.f, w1r_a, w1i_a, w1r_b, w1i_b;
    {
        const int s0 = t * NBINS;
        if (tid == 0) {
            m_a = magg[s0]; m_ny = magg[s0 + 512]; m_b = magg[s0 + 256];
            w1r_a = 1.f; w1i_a = 0.f; w1r_b = 0.f; w1i_b = 1.f;
        } else {
            m_a = magg[s0 + tid]; m_b = magg[s0 + j2];
            w1r_a = tbl[TBL_W1R + tid]; w1i_a = tbl[TBL_W1I + tid];
            w1r_b = tbl[TBL_W1R + j2];  w1i_b = tbl[TBL_W1I + j2];
        }
    }
    // segment ownership for FINAL output only
    const bool extra = (t >= 497);
    int gseg = -1;
    if (tid < 64) gseg = t;
    else if (tid < 128 && extra) gseg = t + 15;
    const int u = tid & 63;
    float iwreg = 0.f;
    if (gseg >= 0) iwreg = iws[(gseg << 6) + u];

    // gather geometry: thread covers samples i0..i0+3 of window [64t, 64t+1023]
    const int q    = tid >> 4;        // sample group -> frame offset
    const int tq   = t + q;
    const int foff = i0 & 63;
    const bool interior = (t >= 15 && t <= NFR - 16);   // all tp in [0,511]

#pragma unroll 1
    for (int it = 1; it <= NITER; ++it) {
        // ---- wait: frames t-15..t+15 at generation it-1 (padded flags) ----
        if (it > 1 && tid < 31) {
            int tp = t - 15 + tid;
            if (tp >= 0 && tp < NFR) {
                const int* fp = fgen + (tp << 4);
                if (flag_load(fp) < it - 1) {
                    do { __builtin_amdgcn_s_sleep(4); } while (flag_load(fp) < it - 1);
                }
            }
        }
        __syncthreads();

        const float* Fs = (it & 1) ? F0 : F1;   // source parity (it-1)&1
        float*       Fd = (it & 1) ? F1 : F0;   // dest parity it&1

        // ---- fused local OLA gather + iws + window -> packed z in C1 ----
        float4 acc;
        if (interior) {
            float4 v0  = coh_load4(&Fs[((tq)      << 10) + foff]);
            float4 v1  = coh_load4(&Fs[((tq - 1)  << 10) + foff + (1 << 6)]);
            float4 v2  = coh_load4(&Fs[((tq - 2)  << 10) + foff + (2 << 6)]);
            float4 v3  = coh_load4(&Fs[((tq - 3)  << 10) + foff + (3 << 6)]);
            float4 v4  = coh_load4(&Fs[((tq - 4)  << 10) + foff + (4 << 6)]);
            float4 v5  = coh_load4(&Fs[((tq - 5)  << 10) + foff + (5 << 6)]);
            float4 v6  = coh_load4(&Fs[((tq - 6)  << 10) + foff + (6 << 6)]);
            float4 v7  = coh_load4(&Fs[((tq - 7)  << 10) + foff + (7 << 6)]);
            float4 v8  = coh_load4(&Fs[((tq - 8)  << 10) + foff + (8 << 6)]);
            float4 v9  = coh_load4(&Fs[((tq - 9)  << 10) + foff + (9 << 6)]);
            float4 v10 = coh_load4(&Fs[((tq - 10) << 10) + foff + (10 << 6)]);
            float4 v11 = coh_load4(&Fs[((tq - 11) << 10) + foff + (11 << 6)]);
            float4 v12 = coh_load4(&Fs[((tq - 12) << 10) + foff + (12 << 6)]);
            float4 v13 = coh_load4(&Fs[((tq - 13) << 10) + foff + (13 << 6)]);
            float4 v14 = coh_load4(&Fs[((tq - 14) << 10) + foff + (14 << 6)]);
            float4 v15 = coh_load4(&Fs[((tq - 15) << 10) + foff + (15 << 6)]);
            float4 s0 = f4add(f4add(v0, v1),  f4add(v2, v3));
            float4 s1 = f4add(f4add(v4, v5),  f4add(v6, v7));
            float4 s2 = f4add(f4add(v8, v9),  f4add(v10, v11));
            float4 s3 = f4add(f4add(v12, v13), f4add(v14, v15));
            acc = f4add(f4add(s0, s1), f4add(s2, s3));
        } else {
            acc = make_float4(0.f, 0.f, 0.f, 0.f);
#pragma unroll
            for (int m = 0; m < 16; ++m) {
                int tp = tq - m;
                if (tp >= 0 && tp < NFR) {
                    float4 x = coh_load4(&Fs[(tp << 10) + foff + (m << 6)]);
                    acc.x += x.x; acc.y += x.y; acc.z += x.z; acc.w += x.w;
                }
            }
        }
        {
            float xx = acc.x * iws4.x;
            float xy = acc.y * iws4.y;
            float xz = acc.z * iws4.z;
            float xw = acc.w * iws4.w;
            sm.C1r[n0]     = xx * w4.x;
            sm.C1i[n0]     = xy * w4.y;
            sm.C1r[n0 + 1] = xz * w4.z;
            sm.C1i[n0 + 1] = xw * w4.w;
        }
        __syncthreads();
        // forward FFT: C1 -> C0
        if (tid < 128) {
            float x0r = sm.C1r[tid],       x0i = sm.C1i[tid];
            float x1r = sm.C1r[tid + 128], x1i = sm.C1i[tid + 128];
            float x2r = sm.C1r[tid + 256], x2i = sm.C1i[tid + 256];
            float x3r = sm.C1r[tid + 384], x3i = sm.C1i[tid + 384];
            float t0r = x0r + x2r, t0i = x0i + x2i;
            float t1r = x0r - x2r, t1i = x0i - x2i;
            float t2r = x1r + x3r, t2i = x1i + x3i;
            float t3r = x1r - x3r, t3i = x1i - x3i;
            float4 vr = make_float4(t0r + t2r, t1r + t3i, t0r - t2r, t1r - t3i);
            float4 vi = make_float4(t0i + t2i, t1i - t3r, t0i - t2i, t1i + t3r);
            ((float4*)sm.C0r)[tid] = vr;
            ((float4*)sm.C0i)[tid] = vi;
        }
        __syncthreads();
        if (tid < 128) r4b<4, 5, false>(sm.C0r, sm.C0i, sm.C1r, sm.C1i, sm.twr, sm.twi, tid);
        __syncthreads();
        if (tid < 128) r4b<16, 3, false>(sm.C1r, sm.C1i, sm.C0r, sm.C0i, sm.twr, sm.twi, tid);
        __syncthreads();
        if (tid < 128) r4b<64, 1, false>(sm.C0r, sm.C0i, sm.C1r, sm.C1i, sm.twr, sm.twi, tid);
        __syncthreads();
        {
            float c = sm.twr[tid], s = sm.twi[tid];
            float x0r = sm.C1r[tid], x0i = sm.C1i[tid];
            float x1r = sm.C1r[tid + 256], x1i = sm.C1i[tid + 256];
            float ar = x1r * c - x1i * s, ai = x1r * s + x1i * c;
            sm.C0r[tid]       = x0r + ar;  sm.C0i[tid]       = x0i + ai;
            sm.C0r[tid + 256] = x0r - ar;  sm.C0i[tid + 256] = x0i - ai;
        }
        __syncthreads();

        // fused unpack + phase projection + iFFT prep: C0 -> C1
        if (tid == 0) {
            float zr = sm.C0r[0], zi = sm.C0i[0];
            float e0 = zr + zi;
            float e5 = zr - zi;
            float X0 = m_a  * e0 / fmaxf(1e-8f, fabsf(e0));
            float X5 = m_ny * e5 / fmaxf(1e-8f, fabsf(e5));
            sm.C1r[0] = (X0 + X5) * (1.0f / 1024.0f);
            sm.C1i[0] = (X0 - X5) * (1.0f / 1024.0f);
            float z6r = sm.C0r[256], z6i = sm.C0i[256];
            float sc6 = m_b / fmaxf(1e-8f, sqrtf(z6r * z6r + z6i * z6i));
            float X6r = z6r * sc6, X6i = -z6i * sc6;
            sm.C1r[256] = X6r * (2.0f / 1024.0f);
            sm.C1i[256] = -X6i * (2.0f / 1024.0f);
        } else {
            float zr = sm.C0r[tid], zi = sm.C0i[tid];
            float ur = sm.C0r[j2],  ui = sm.C0i[j2];
            float er = 0.5f * (zr + ur), ei = 0.5f * (zi - ui);
            float dr = zr - ur,          di = zi + ui;
            float odr = 0.5f * di, odi = -0.5f * dr;
            float e1r = er + w1r_a * odr + w1i_a * odi;
            float e1i = ei + w1r_a * odi - w1i_a * odr;
            float e2r =  er + w1r_b * odr - w1i_b * odi;
            float e2i = -ei - w1r_b * odi - w1i_b * odr;
            float sc1 = m_a / fmaxf(1e-8f, sqrtf(e1r * e1r + e1i * e1i));
            float sc2 = m_b / fmaxf(1e-8f, sqrtf(e2r * e2r + e2i * e2i));
            float X1r = e1r * sc1, X1i = e1i * sc1;
            float X2r = e2r * sc2, X2i = e2i * sc2;
            float Er = X1r + X2r, Ei = X1i - X2i;
            float Dr = X1r - X2r, Di = X1i + X2i;
            float wdr = w1r_a * Dr - w1i_a * Di, wdi = w1r_a * Di + w1i_a * Dr;
            sm.C1r[tid] = (Er - wdi) * (1.0f / 1024.0f);
            sm.C1i[tid] = (Ei + wdr) * (1.0f / 1024.0f);
            float wdr2 = -w1r_b * Dr - w1i_b * Di, wdi2 = w1r_b * Di - w1i_b * Dr;
            sm.C1r[j2] = (Er - wdi2) * (1.0f / 1024.0f);
            sm.C1i[j2] = (-Ei + wdr2) * (1.0f / 1024.0f);
        }
        __syncthreads();

        // inverse FFT: C1 -> C0
        if (tid < 128) {
            float x0r = sm.C1r[tid],       x0i = sm.C1i[tid];
            float x1r = sm.C1r[tid + 128], x1i = sm.C1i[tid + 128];
            float x2r = sm.C1r[tid + 256], x2i = sm.C1i[tid + 256];
            float x3r = sm.C1r[tid + 384], x3i = sm.C1i[tid + 384];
            float t0r = x0r + x2r, t0i = x0i + x2i;
            float t1r = x0r - x2r, t1i = x0i - x2i;
            float t2r = x1r + x3r, t2i = x1i + x3i;
            float t3r = x1r - x3r, t3i = x1i - x3i;
            float4 vr = make_float4(t0r + t2r, t1r - t3i, t0r - t2r, t1r + t3i);
            float4 vi = make_float4(t0i + t2i, t1i + t3r, t0i - t2i, t1i - t3r);
            ((float4*)sm.C0r)[tid] = vr;
            ((float4*)sm.C0i)[tid] = vi;
        }
        __syncthreads();
        if (tid < 128) r4b<4, 5, true>(sm.C0r, sm.C0i, sm.C1r, sm.C1i, sm.twr, sm.twi, tid);
        __syncthreads();
        if (tid < 128) r4b<16, 3, true>(sm.C1r, sm.C1i, sm.C0r, sm.C0i, sm.twr, sm.twi, tid);
        __syncthreads();
        if (tid < 128) r4b<64, 1, true>(sm.C0r, sm.C0i, sm.C1r, sm.C1i, sm.twr, sm.twi, tid);
        __syncthreads();
        {
            float c = sm.twr[tid], s = -sm.twi[tid];
            float x0r = sm.C1r[tid], x0i = sm.C1i[tid];
            float x1r = sm.C1r[tid + 256], x1i = sm.C1i[tid + 256];
            float ar = x1r * c - x1i * s, ai = x1r * s + x1i * c;
            sm.C0r[tid]       = x0r + ar;  sm.C0i[tid]       = x0i + ai;
            sm.C0r[tid + 256] = x0r - ar;  sm.C0i[tid + 256] = x0i - ai;
        }
        __syncthreads();

        // store windowed frame into dest parity, publish fgen[t]=it
        {
            float4 o;
            o.x = w4.x * sm.C0r[n0];
            o.y = w4.y * sm.C0i[n0];
            o.z = w4.z * sm.C0r[n0 + 1];
            o.w = w4.w * sm.C0i[n0 + 1];
            coh_store4(&Fd[(t << 10) + i0], o);
        }
        __syncthreads();                 // drain vmcnt: F[t]@it at L3
        if (tid == 0)
            flag_store(fgen + (t << 4), it);
    }

    // ===== final non-redundant OLA @ gen NITER (even -> parity 0 -> F0) =====
    if (gseg >= 0 && u < 16) {
        int tp = gseg - u;
        if (tp >= 0 && tp < NFR) {
            const int* fp = fgen + (tp << 4);
            if (flag_load(fp) < NITER) {
                do { __builtin_amdgcn_s_sleep(4); } while (flag_load(fp) < NITER);
            }
        }
    }
    __syncthreads();
    if (gseg >= 0) {
        float acc = 0.f;
#pragma unroll
        for (int m = 0; m < 16; ++m) {
            int tp = gseg - m;
            if (tp >= 0 && tp < NFR)
                acc += coh_load1(&F0[(tp << 10) + u + (m << 6)]);
        }
        out[(gseg << 6) + u] = acc * iwreg;
    }
}

extern "C" void kernel_launch(void* const* d_in, const int* in_sizes, int n_in,
                              void* d_out, int out_size, void* d_ws, size_t ws_size,
                              hipStream_t stream) {
    const float* mel    = (const float*)d_in[0];
    const float* invmel = (const float*)d_in[1];
    float* out = (float*)d_out;
    float* ws  = (float*)d_ws;

    k_init<<<NFR, NT, 0, stream>>>(mel, invmel, ws);
    k_persist<<<NB, NT, 0, stream>>>(ws, out);
}